// Round 5
// baseline (603.361 us; speedup 1.0000x reference)
//
#include <hip/hip_runtime.h>
#include <hip/hip_bf16.h>
#include <stdint.h>

#define B_ 2
#define S_ 2048
#define D_ 1024
#define H_ 16
#define HD_ 64

typedef __attribute__((ext_vector_type(8))) short short8v;
typedef __attribute__((ext_vector_type(4))) float f32x4;

__device__ __forceinline__ unsigned short f2bf(float f) {
  union { float f; unsigned int u; } c; c.f = f;
  unsigned int u = c.u;
  unsigned int r = u + 0x7FFFu + ((u >> 16) & 1u);
  return (unsigned short)(r >> 16);
}

__device__ __forceinline__ f32x4 mfma16(short8v a, short8v b, f32x4 c) {
  return __builtin_amdgcn_mfma_f32_16x16x32_bf16(a, b, c, 0, 0, 0);
}

// ---------------- fused fp32 -> bf16 converts (x, W_in, W_out) ----------------
#define NX4_ (B_ * S_ * D_ / 4)     // 1048576 float4 groups
#define NW4_ (D_ * D_ / 4)          // 262144
__global__ __launch_bounds__(256) void convert3(
    const float* __restrict__ x, const float* __restrict__ wi, const float* __restrict__ wo,
    unsigned short* __restrict__ xb, unsigned short* __restrict__ wib,
    unsigned short* __restrict__ wob) {
  int i = blockIdx.x * 256 + threadIdx.x;
  const float* src; unsigned short* dst; int j;
  if (i < NX4_)              { src = x;  dst = xb;  j = i; }
  else if (i < NX4_ + NW4_)  { src = wi; dst = wib; j = i - NX4_; }
  else                       { src = wo; dst = wob; j = i - NX4_ - NW4_; }
  float4 v = reinterpret_cast<const float4*>(src)[j];
  ushort4 o;
  o.x = f2bf(v.x); o.y = f2bf(v.y); o.z = f2bf(v.z); o.w = f2bf(v.w);
  reinterpret_cast<ushort4*>(dst)[j] = o;
}

// ---- no-LDS GEMM: C[M][N] = A[M][K] @ B[N][K]^T + bias; 64x64 blocks, 4 waves ----
// Each wave computes a 32x32 quadrant; fragments loaded directly from global.
template<bool OUT_BF16, bool BIAS_ROW>
__global__ __launch_bounds__(256) void gemm_nolds(
    const unsigned short* __restrict__ A,   // [M][K] bf16
    const unsigned short* __restrict__ Bm,  // [N][K] bf16
    const float* __restrict__ bias,
    void* __restrict__ Cout, int M, int N, int K)
{
  const int tid = threadIdx.x;
  const int lane = tid & 63;
  const int w = tid >> 6;
  const int bM = blockIdx.y * 64, bN = blockIdx.x * 64;
  const int wr = (w >> 1) * 32, wc = (w & 1) * 32;
  const int lr = lane & 15, lk = (lane >> 4) * 8;

  const unsigned short* a0 = A + (size_t)(bM + wr + lr) * K + lk;
  const unsigned short* a1 = a0 + (size_t)16 * K;
  const unsigned short* b0 = Bm + (size_t)(bN + wc + lr) * K + lk;
  const unsigned short* b1 = b0 + (size_t)16 * K;

  f32x4 acc[2][2] = {};
#pragma unroll 2
  for (int k0 = 0; k0 < K; k0 += 32) {
    short8v av0 = *reinterpret_cast<const short8v*>(a0 + k0);
    short8v av1 = *reinterpret_cast<const short8v*>(a1 + k0);
    short8v bv0 = *reinterpret_cast<const short8v*>(b0 + k0);
    short8v bv1 = *reinterpret_cast<const short8v*>(b1 + k0);
    acc[0][0] = mfma16(av0, bv0, acc[0][0]);
    acc[0][1] = mfma16(av0, bv1, acc[0][1]);
    acc[1][0] = mfma16(av1, bv0, acc[1][0]);
    acc[1][1] = mfma16(av1, bv1, acc[1][1]);
  }

  const int r0 = wr + (lane >> 4) * 4;
  const int c0 = wc + lr;
#pragma unroll
  for (int m = 0; m < 2; m++) {
#pragma unroll
    for (int n = 0; n < 2; n++) {
      const int gc = bN + c0 + n * 16;
      float bcol = BIAS_ROW ? 0.0f : bias[gc];
#pragma unroll
      for (int j = 0; j < 4; j++) {
        const int gr = bM + r0 + m * 16 + j;
        float v = acc[m][n][j] + (BIAS_ROW ? bias[gr] : bcol);
        if (OUT_BF16)
          reinterpret_cast<unsigned short*>(Cout)[(size_t)gr * N + gc] = f2bf(v);
        else
          reinterpret_cast<float*>(Cout)[(size_t)gr * N + gc] = v;
      }
    }
  }
}

// ---------------- causal per-head mix, no-LDS, 32-row tiles ----------------
__device__ __forceinline__ short8v pack8(f32x4 lo, f32x4 hi) {
  short8v r;
#pragma unroll
  for (int e = 0; e < 4; e++) {
    r[e]     = (short)f2bf(lo[e]);
    r[4 + e] = (short)f2bf(hi[e]);
  }
  return r;
}

__device__ __forceinline__ short8v pack8_mask(f32x4 lo, f32x4 hi, int lk, int lim) {
  short8v r;
#pragma unroll
  for (int e = 0; e < 4; e++) {
    float v0 = (lk + e     <= lim) ? lo[e] : 0.0f;
    float v1 = (lk + 4 + e <= lim) ? hi[e] : 0.0f;
    r[e]     = (short)f2bf(v0);
    r[4 + e] = (short)f2bf(v1);
  }
  return r;
}

__global__ __launch_bounds__(256) void gemm_mix(
    const float* __restrict__ Wmix,          // [H][S][S] fp32
    const unsigned short* __restrict__ xpT,  // [D][B*S] bf16: row h*64+d, col b*2048+t
    unsigned short* __restrict__ mixed)      // [B*S][D] bf16
{
  const int tid = threadIdx.x;
  const int lane = tid & 63;
  const int w = tid >> 6;
  const int h = blockIdx.y;
  const int xi = blockIdx.x;                 // long/short interleave for balance
  const int tilei = (xi & 1) ? (63 - (xi >> 1)) : (xi >> 1);
  const int T0 = tilei * 32;
  const int wc = w * 32;                     // 4 waves cover 128 output cols (b,d)
  const int lr = lane & 15, lk = (lane >> 4) * 8;

  // A (W_mix) fragment rows: t = T0 + m*16 + lr  (all 4 waves identical -> L1 broadcast)
  const float* aw0 = Wmix + ((size_t)h * S_ + T0 + lr) * S_ + lk;
  const float* aw1 = aw0 + (size_t)16 * S_;
  // B fragment rows: output col cc -> b = cc>>6, d = cc&63 -> xpT row h*64+d, col b*2048+k
  const int cc0 = wc + lr, cc1 = wc + 16 + lr;
  const unsigned short* bp0 =
      xpT + ((size_t)(h * HD_) + (cc0 & 63)) * (B_ * S_) + (cc0 >> 6) * S_ + lk;
  const unsigned short* bp1 =
      xpT + ((size_t)(h * HD_) + (cc1 & 63)) * (B_ * S_) + (cc1 >> 6) * S_ + lk;

  f32x4 acc[2][2] = {};

#pragma unroll 2
  for (int k0 = 0; k0 < T0; k0 += 32) {      // strictly-below-diagonal steps: no mask
    f32x4 a00 = *reinterpret_cast<const f32x4*>(aw0 + k0);
    f32x4 a01 = *reinterpret_cast<const f32x4*>(aw0 + k0 + 4);
    f32x4 a10 = *reinterpret_cast<const f32x4*>(aw1 + k0);
    f32x4 a11 = *reinterpret_cast<const f32x4*>(aw1 + k0 + 4);
    short8v av0 = pack8(a00, a01);
    short8v av1 = pack8(a10, a11);
    short8v bv0 = *reinterpret_cast<const short8v*>(bp0 + k0);
    short8v bv1 = *reinterpret_cast<const short8v*>(bp1 + k0);
    acc[0][0] = mfma16(av0, bv0, acc[0][0]);
    acc[0][1] = mfma16(av0, bv1, acc[0][1]);
    acc[1][0] = mfma16(av1, bv0, acc[1][0]);
    acc[1][1] = mfma16(av1, bv1, acc[1][1]);
  }
  {                                          // diagonal step k0 = T0: causal mask
    const int k0 = T0;
    f32x4 a00 = *reinterpret_cast<const f32x4*>(aw0 + k0);
    f32x4 a01 = *reinterpret_cast<const f32x4*>(aw0 + k0 + 4);
    f32x4 a10 = *reinterpret_cast<const f32x4*>(aw1 + k0);
    f32x4 a11 = *reinterpret_cast<const f32x4*>(aw1 + k0 + 4);
    short8v av0 = pack8_mask(a00, a01, lk, lr);        // keep col-T0 <= lr
    short8v av1 = pack8_mask(a10, a11, lk, 16 + lr);   // keep col-T0 <= 16+lr
    short8v bv0 = *reinterpret_cast<const short8v*>(bp0 + k0);
    short8v bv1 = *reinterpret_cast<const short8v*>(bp1 + k0);
    acc[0][0] = mfma16(av0, bv0, acc[0][0]);
    acc[0][1] = mfma16(av0, bv1, acc[0][1]);
    acc[1][0] = mfma16(av1, bv0, acc[1][0]);
    acc[1][1] = mfma16(av1, bv1, acc[1][1]);
  }

  const int r0 = (lane >> 4) * 4;
#pragma unroll
  for (int m = 0; m < 2; m++)
#pragma unroll
    for (int n = 0; n < 2; n++) {
      const int cc = wc + lr + n * 16;
      const int bb = cc >> 6, dd = cc & 63;
#pragma unroll
      for (int j = 0; j < 4; j++) {
        const int tt = T0 + r0 + m * 16 + j;
        mixed[((size_t)(bb * S_ + tt)) * D_ + h * HD_ + dd] = f2bf(acc[m][n][j]);
      }
    }
}

extern "C" void kernel_launch(void* const* d_in, const int* in_sizes, int n_in,
                              void* d_out, int out_size, void* d_ws, size_t ws_size,
                              hipStream_t stream) {
  const float* x     = (const float*)d_in[0];
  const float* W_in  = (const float*)d_in[1];
  const float* b_in  = (const float*)d_in[2];
  const float* W_mix = (const float*)d_in[3];
  const float* W_out = (const float*)d_in[4];
  const float* b_out = (const float*)d_in[5];

  char* ws = (char*)d_ws;
  unsigned short* xb    = (unsigned short*)(ws);                       // 8MB; dead after gemm1
  unsigned short* xpT   = (unsigned short*)(ws + 8u * 1024u * 1024u);  // 8MB
  unsigned short* wib   = (unsigned short*)(ws + 16u * 1024u * 1024u); // 2MB
  unsigned short* wob   = (unsigned short*)(ws + 18u * 1024u * 1024u); // 2MB
  unsigned short* mixed = xb;                                          // reuse

  convert3<<<dim3((NX4_ + 2 * NW4_) / 256), dim3(256), 0, stream>>>(
      x, W_in, W_out, xb, wib, wob);

  // xpT[d][token] = W_in @ x^T + b_in (bias per row d)
  gemm_nolds<true, true><<<dim3(B_ * S_ / 64, D_ / 64), dim3(256), 0, stream>>>(
      wib, xb, b_in, (void*)xpT, D_, B_ * S_, D_);

  // mixed[token][D]
  gemm_mix<<<dim3(S_ / 32, H_), dim3(256), 0, stream>>>(W_mix, xpT, mixed);

  // out[token][dout] = mixed @ W_out^T + b_out (bias per col dout)
  gemm_nolds<false, false><<<dim3(D_ / 64, B_ * S_ / 64), dim3(256), 0, stream>>>(
      mixed, wob, b_out, (void*)d_out, B_ * S_, D_, D_);
}